// Round 6
// baseline (199.517 us; speedup 1.0000x reference)
//
#include <hip/hip_runtime.h>
#include <cmath>

typedef short short8 __attribute__((ext_vector_type(8)));
typedef float f32x16 __attribute__((ext_vector_type(16)));

#define EPSF 1.1920929e-07f

// ---------------- LDS layout (bytes), total 138240 ----------------
#define LDS_XA  0        // [64][24] ushort bf16 xA (cols 16-23 pad, never read)
#define LDS_A1H 3072     // [64][264] ushort
#define LDS_A1W 36864    // [64][264] ushort
#define LDS_A2H 70656    // [64][264] ushort
#define LDS_A2W 104448   // [64][264] ushort
#define LDS_H32 3072     // [64][16] f32 (overlays A1H; written P3a, read P3b)
#define LDS_TOTAL 138240

// ---------------- packed weights (ushort elements) in d_ws ----------------
// Swapped-operand packing: A' = W^T with column permutation such that
// MFMA D reg rr (lane half q) holds output channel  base + q*16 + rr.
// A-frag: lane l holds A'[m=l&31][k=(l>>5)*8+e];  A'[m][k] = W[kt*16+k][chan(m)]
#define OFF1H 0        // 8 tiles x 1 kt
#define OFF1W 4096
#define OFF2H 8192     // 8 tiles x 16 kt
#define OFF2W 73728
#define OFF3W 139264   // 16 tiles x 16 kt (chan stride 32)
#define OFF3H 270336   // 16 tiles x 16 kt (chan stride 33, k=0..31)
#define OFFH32 401408  // 1 tile x 16 kt  (16 valid ch: col = rr*33+32, q==0 only)

__device__ __forceinline__ unsigned short f2bf(float f) {   // round-half-up
  union { float f; unsigned u; } v; v.f = f;
  return (unsigned short)((v.u + 0x8000u) >> 16);
}
__device__ __forceinline__ float sp_eps(float v) {          // softplus + EPS
  return fmaxf(v, 0.f) + __logf(1.f + __expf(-fabsf(v))) + EPSF;
}
__device__ __forceinline__ int chanm(int m) {               // (rr,q) of position m
  return (((m >> 2) & 1) << 4) + (m & 3) + ((m >> 3) << 2);
}

__global__ void pack_weights(const float* __restrict__ hW1, const float* __restrict__ wW1,
                             const float* __restrict__ hW2, const float* __restrict__ wW2,
                             const float* __restrict__ hW3, const float* __restrict__ wW3,
                             unsigned short* __restrict__ out) {
  int bid = blockIdx.x, l = threadIdx.x;
  int m = l & 31;
  const float* W; unsigned short* dst; int tile, col, NC;
  if (bid < 8)        { W = hW1; dst = out + OFF1H;  tile = bid;       col = tile * 32 + chanm(m); NC = 256; }
  else if (bid < 16)  { W = wW1; dst = out + OFF1W;  tile = bid - 8;   col = tile * 32 + chanm(m); NC = 256; }
  else if (bid < 144) { W = hW2; dst = out + OFF2H;  tile = bid - 16;  col = (tile >> 4) * 32 + chanm(m); NC = 256; }
  else if (bid < 272) { W = wW2; dst = out + OFF2W;  tile = bid - 144; col = (tile >> 4) * 32 + chanm(m); NC = 256; }
  else if (bid < 528) { W = wW3; dst = out + OFF3W;  tile = bid - 272; col = (tile >> 4) * 32 + chanm(m); NC = 512; }
  else if (bid < 784) { W = hW3; dst = out + OFF3H;  tile = bid - 528; col = (tile >> 4) * 33 + chanm(m); NC = 528; }
  else {
    W = hW3; dst = out + OFFH32; tile = bid - 784;
    int q = (m >> 2) & 1, rr = (m & 3) + ((m >> 3) << 2);
    col = q ? -1 : rr * 33 + 32; NC = 528;
  }
  int kt = (bid < 16) ? 0 : (tile & 15);
  int K  = (bid < 16) ? 16 : 256;
  int k0 = kt * 16 + (l >> 5) * 8;
  short8 v;
  #pragma unroll
  for (int e = 0; e < 8; e++) {
    float f = (col >= 0 && (k0 + e) < K) ? W[(k0 + e) * NC + col] : 0.f;
    v[e] = (short)f2bf(f);
  }
  *(short8*)(dst + (tile * 64 + l) * 8) = v;
}

// relu + pack 16 consecutive channels -> two ds_write_b128
__device__ __forceinline__ void store_relu16(unsigned short* dstRow, f32x16 a) {
  uint4 p0, p1;
  unsigned pk[8];
  #pragma unroll
  for (int j = 0; j < 8; j++) {
    unsigned lo = f2bf(fmaxf(a[2 * j], 0.f));
    unsigned hi = f2bf(fmaxf(a[2 * j + 1], 0.f));
    pk[j] = lo | (hi << 16);
  }
  p0.x = pk[0]; p0.y = pk[1]; p0.z = pk[2]; p0.w = pk[3];
  p1.x = pk[4]; p1.y = pk[5]; p1.z = pk[6]; p1.w = pk[7];
  *(uint4*)(dstRow) = p0;
  *(uint4*)(dstRow + 8) = p1;
}

__global__ __launch_bounds__(1024, 4) void fused_kernel(
    const float* __restrict__ x,
    const float* __restrict__ hb1, const float* __restrict__ hb2, const float* __restrict__ hb3,
    const float* __restrict__ wb1, const float* __restrict__ wb2, const float* __restrict__ wb3,
    const unsigned short* __restrict__ pw,
    float* __restrict__ y) {
  extern __shared__ char lds[];
  const int t = threadIdx.x;
  const int w = t >> 6, l = t & 63, q = l >> 5, r32 = l & 31;
  const int r0 = blockIdx.x * 64;

  unsigned short* XA  = (unsigned short*)(lds + LDS_XA);
  unsigned short* A1H = (unsigned short*)(lds + LDS_A1H);
  unsigned short* A1W = (unsigned short*)(lds + LDS_A1W);
  unsigned short* A2H = (unsigned short*)(lds + LDS_A2H);
  unsigned short* A2W = (unsigned short*)(lds + LDS_A2W);
  float* H32 = (float*)(lds + LDS_H32);

  // ---- P0: load x, emit y even cols, stage xA bf16 [64][24] ----
  if (t < 512) {
    int row = t >> 3, c4 = t & 7;
    float4 v = *(const float4*)(x + (r0 + row) * 32 + c4 * 4);
    y[(r0 + row) * 32 + c4 * 4] = v.x;
    y[(r0 + row) * 32 + c4 * 4 + 2] = v.z;
    unsigned short* xa = XA + row * 24 + c4 * 2;
    xa[0] = f2bf(v.x); xa[1] = f2bf(v.z);
  }
  __syncthreads();

  const int net = w >> 3, tc = w & 7;     // P1/P2 roles: 8 waves h-net, 8 w-net
  unsigned short* A1n = net ? A1W : A1H;
  unsigned short* A2n = net ? A2W : A2H;

  // ---- P1: L1 (K=16, one MFMA per rg) ----
  {
    const unsigned short* pA = pw + (net ? OFF1W : OFF1H) + tc * 512;
    const float* b1 = net ? wb1 : hb1;
    f32x16 a0, a1;
    #pragma unroll
    for (int rr = 0; rr < 16; rr++) { float bv = b1[tc * 32 + q * 16 + rr]; a0[rr] = bv; a1[rr] = bv; }
    short8 af = *(const short8*)(pA + l * 8);
    short8 b0 = *(const short8*)(XA + r32 * 24 + q * 8);
    short8 b1f = *(const short8*)(XA + (32 + r32) * 24 + q * 8);
    a0 = __builtin_amdgcn_mfma_f32_32x32x16_bf16(af, b0, a0, 0, 0, 0);
    a1 = __builtin_amdgcn_mfma_f32_32x32x16_bf16(af, b1f, a1, 0, 0, 0);
    store_relu16(A1n + r32 * 264 + tc * 32 + q * 16, a0);
    store_relu16(A1n + (32 + r32) * 264 + tc * 32 + q * 16, a1);
  }
  __syncthreads();

  // ---- P2: L2 (K=256, A-frag shared across both row-groups) ----
  {
    const unsigned short* pA = pw + (net ? OFF2W : OFF2H) + tc * 16 * 512;
    const float* b2 = net ? wb2 : hb2;
    f32x16 a0, a1;
    #pragma unroll
    for (int rr = 0; rr < 16; rr++) { float bv = b2[tc * 32 + q * 16 + rr]; a0[rr] = bv; a1[rr] = bv; }
    #pragma unroll
    for (int kt = 0; kt < 16; kt++) {
      short8 af = *(const short8*)(pA + kt * 512 + l * 8);
      short8 b0 = *(const short8*)(A1n + r32 * 264 + kt * 16 + q * 8);
      short8 b1f = *(const short8*)(A1n + (32 + r32) * 264 + kt * 16 + q * 8);
      a0 = __builtin_amdgcn_mfma_f32_32x32x16_bf16(af, b0, a0, 0, 0, 0);
      a1 = __builtin_amdgcn_mfma_f32_32x32x16_bf16(af, b1f, a1, 0, 0, 0);
    }
    store_relu16(A2n + r32 * 264 + tc * 32 + q * 16, a0);
    store_relu16(A2n + (32 + r32) * 264 + tc * 32 + q * 16, a1);
  }
  __syncthreads();

  // ---- P3a: G3 — wave w owns d = w; spline data stays in registers ----
  const int d = w;
  f32x16 ew0, ew1, hh0, hh1;
  #pragma unroll
  for (int rr = 0; rr < 16; rr++) {
    float wv = wb3[d * 32 + q * 16 + rr];
    float hv = hb3[d * 33 + q * 16 + rr];
    ew0[rr] = wv; ew1[rr] = wv; hh0[rr] = hv; hh1[rr] = hv;
  }
  {
    const unsigned short* pAW = pw + OFF3W + d * 16 * 512;
    const unsigned short* pAH = pw + OFF3H + d * 16 * 512;
    #pragma unroll
    for (int kt = 0; kt < 16; kt++) {
      short8 aw = *(const short8*)(pAW + kt * 512 + l * 8);
      short8 bw0 = *(const short8*)(A2W + r32 * 264 + kt * 16 + q * 8);
      short8 bw1 = *(const short8*)(A2W + (32 + r32) * 264 + kt * 16 + q * 8);
      ew0 = __builtin_amdgcn_mfma_f32_32x32x16_bf16(aw, bw0, ew0, 0, 0, 0);
      ew1 = __builtin_amdgcn_mfma_f32_32x32x16_bf16(aw, bw1, ew1, 0, 0, 0);
      short8 ah = *(const short8*)(pAH + kt * 512 + l * 8);
      short8 bh0 = *(const short8*)(A2H + r32 * 264 + kt * 16 + q * 8);
      short8 bh1 = *(const short8*)(A2H + (32 + r32) * 264 + kt * 16 + q * 8);
      hh0 = __builtin_amdgcn_mfma_f32_32x32x16_bf16(ah, bh0, hh0, 0, 0, 0);
      hh1 = __builtin_amdgcn_mfma_f32_32x32x16_bf16(ah, bh1, hh1, 0, 0, 0);
    }
  }
  // elementwise: e = exp(raw_w), h = softplus(raw_h)+EPS — in registers
  #pragma unroll
  for (int rr = 0; rr < 16; rr++) {
    ew0[rr] = __expf(ew0[rr]); ew1[rr] = __expf(ew1[rr]);
    hh0[rr] = sp_eps(hh0[rr]); hh1[rr] = sp_eps(hh1[rr]);
  }
  // h32 tile: waves 14 (rg0) and 15 (rg1)
  if (w >= 14) {
    int rg = w - 14;
    f32x16 a32;
    #pragma unroll
    for (int rr = 0; rr < 16; rr++) a32[rr] = 0.f;
    const unsigned short* pA32 = pw + OFFH32;
    #pragma unroll
    for (int kt = 0; kt < 16; kt++) {
      short8 af = *(const short8*)(pA32 + kt * 512 + l * 8);
      short8 bf = *(const short8*)(A2H + (rg * 32 + r32) * 264 + kt * 16 + q * 8);
      a32 = __builtin_amdgcn_mfma_f32_32x32x16_bf16(af, bf, a32, 0, 0, 0);
    }
    if (q == 0) {   // reg rr holds channel d'=rr
      float* o = H32 + (rg * 32 + r32) * 16;
      #pragma unroll
      for (int g = 0; g < 4; g++) {
        float4 v;
        v.x = sp_eps(a32[g * 4 + 0] + hb3[(g * 4 + 0) * 33 + 32]);
        v.y = sp_eps(a32[g * 4 + 1] + hb3[(g * 4 + 1) * 33 + 32]);
        v.z = sp_eps(a32[g * 4 + 2] + hb3[(g * 4 + 2) * 33 + 32]);
        v.w = sp_eps(a32[g * 4 + 3] + hb3[(g * 4 + 3) * 33 + 32]);
        *(float4*)(o + g * 4) = v;
      }
    }
  }
  __syncthreads();

  // ---- P3b: spline, 2 row-groups; pair = (l, l^32), half = q ----
  #pragma unroll
  for (int rg = 0; rg < 2; rg++) {
    f32x16 e  = rg ? ew1 : ew0;
    f32x16 hh = rg ? hh1 : hh0;
    int row = rg * 32 + r32;
    float se = 0.f;
    #pragma unroll
    for (int k = 0; k < 16; k++) se += e[k];
    float so = __shfl_xor(se, 32);
    float s = se + so;
    float oth0 = __shfl_xor(hh[0], 32);
    float h32v = H32[row * 16 + d];
    float hh16 = q ? h32v : oth0;          // h[16] for q=0, h[32] for q=1
    float xbv = x[(r0 + row) * 32 + 2 * d + 1];
    float xbs = xbv * s;
    float bl = q ? so : 0.f;
    int fnd = (xbs >= bl) ? 1 : 0;
    float cl2 = 0.f, sxl = bl, sew = e[0], shl = hh[0], shr = hh[1], scl2 = 0.f;
    #pragma unroll
    for (int k = 0; k < 16; k++) {
      float hn = (k < 15) ? hh[k + 1] : hh16;
      bool c = (xbs >= bl);
      sxl  = c ? bl    : sxl;
      sew  = c ? e[k]  : sew;
      shl  = c ? hh[k] : shl;
      shr  = c ? hn    : shr;
      scl2 = c ? cl2   : scl2;
      cl2 += (hh[k] + hn) * e[k];
      bl  += e[k];
    }
    float cl2o = __shfl_xor(cl2, 32);
    float S2 = cl2 + cl2o;
    if (q) scl2 += cl2o;                   // globalize upper half's prefix
    int   o_fnd  = __shfl_xor(fnd, 32);
    float o_sxl  = __shfl_xor(sxl, 32);
    float o_sew  = __shfl_xor(sew, 32);
    float o_shl  = __shfl_xor(shl, 32);
    float o_shr  = __shfl_xor(shr, 32);
    float o_scl2 = __shfl_xor(scl2, 32);
    bool other = q ? (fnd == 0) : (o_fnd != 0);
    float gsxl  = other ? o_sxl  : sxl;
    float gsew  = other ? o_sew  : sew;
    float gshl  = other ? o_shl  : shl;
    float gshr  = other ? o_shr  : shr;
    float gscl2 = other ? o_scl2 : scl2;
    float alpha = (xbs - gsxl) / (gsew + EPSF);
    float yv = (gscl2 + (alpha * alpha * (gshr - gshl) + 2.f * alpha * gshl) * gsew) / S2;
    if (q == 0) y[(r0 + row) * 32 + 2 * d + 1] = yv;
  }
}

extern "C" void kernel_launch(void* const* d_in, const int* in_sizes, int n_in,
                              void* d_out, int out_size, void* d_ws, size_t ws_size,
                              hipStream_t stream) {
  const float* x   = (const float*)d_in[0];
  const float* hW1 = (const float*)d_in[1];
  const float* hb1 = (const float*)d_in[2];
  const float* hW2 = (const float*)d_in[3];
  const float* hb2 = (const float*)d_in[4];
  const float* hW3 = (const float*)d_in[5];
  const float* hb3 = (const float*)d_in[6];
  const float* wW1 = (const float*)d_in[7];
  const float* wb1 = (const float*)d_in[8];
  const float* wW2 = (const float*)d_in[9];
  const float* wb2 = (const float*)d_in[10];
  const float* wW3 = (const float*)d_in[11];
  const float* wb3 = (const float*)d_in[12];
  unsigned short* pw = (unsigned short*)d_ws;

  pack_weights<<<800, 64, 0, stream>>>(hW1, wW1, hW2, wW2, hW3, wW3, pw);

  hipFuncSetAttribute((const void*)fused_kernel,
                      hipFuncAttributeMaxDynamicSharedMemorySize, LDS_TOTAL);
  fused_kernel<<<2048, 1024, LDS_TOTAL, stream>>>(
      x, hb1, hb2, hb3, wb1, wb2, wb3, pw, (float*)d_out);
}